// Round 6
// baseline (3050.252 us; speedup 1.0000x reference)
//
#include <hip/hip_runtime.h>
#include <hip/hip_bf16.h>

#define SELU_LAM   1.0507009873554805f
#define SELU_ALPHA 1.6732632423543772f

// 64 nodes per bucket
#define NBSH 6
#define NPB  64

__device__ __forceinline__ float selu_f(float v) {
    return v > 0.0f ? SELU_LAM * v
                    : (SELU_LAM * SELU_ALPHA) * (expf(v) - 1.0f);
}

__device__ __forceinline__ unsigned bf16r(float f) {   // RNE f32->bf16 bits
    unsigned u = __float_as_uint(f);
    return (u + 0x7FFFu + ((u >> 16) & 1u)) >> 16;
}

// ------------------------------------------- x -> bf16, deinterleaved pairs
// xb[row*64 + l] = bf16(x[row*128 + l]) | bf16(x[row*128 + l + 64]) << 16

__global__ __launch_bounds__(256) void to_bf16(const float* __restrict__ x,
                                               uint* __restrict__ xb, int total) {
    int i = blockIdx.x * 256 + threadIdx.x;   // one uint each; total = N*64
    if (i >= total) return;
    int row = i >> 6, l = i & 63;
    float a = x[(size_t)row * 128 + l];
    float b = x[(size_t)row * 128 + l + 64];
    xb[i] = bf16r(a) | (bf16r(b) << 16);
}

// ---------------------------------------------------------------- bucketing

// LDS-privatized bucket histogram (B <= 2048)
__global__ __launch_bounds__(256) void bucket_hist(const int* __restrict__ edst,
                                                   int* __restrict__ bcnt, int E, int B) {
    __shared__ int lc[2048];
    for (int i = threadIdx.x; i < B; i += 256) lc[i] = 0;
    __syncthreads();
    int tid = blockIdx.x * 256 + threadIdx.x;
    int stride = gridDim.x * 256;
    int n4 = E >> 2;
    for (int j = tid; j < n4; j += stride) {
        int4 d = ((const int4*)edst)[j];
        atomicAdd(&lc[d.x >> NBSH], 1);
        atomicAdd(&lc[d.y >> NBSH], 1);
        atomicAdd(&lc[d.z >> NBSH], 1);
        atomicAdd(&lc[d.w >> NBSH], 1);
    }
    for (int j = (n4 << 2) + tid; j < E; j += stride) atomicAdd(&lc[edst[j] >> NBSH], 1);
    __syncthreads();
    for (int i = threadIdx.x; i < B; i += 256) if (lc[i]) atomicAdd(&bcnt[i], lc[i]);
}

// single-block exclusive scan of bucket counts (B <= 2048)
__global__ __launch_bounds__(1024) void bucket_scan(const int* __restrict__ bcnt,
                                                    int* __restrict__ boff,
                                                    int* __restrict__ bfill, int B, int E) {
    __shared__ int buf[1024];
    int t = threadIdx.x;
    int a = (2 * t     < B) ? bcnt[2 * t]     : 0;
    int b = (2 * t + 1 < B) ? bcnt[2 * t + 1] : 0;
    buf[t] = a + b; __syncthreads();
    for (int d = 1; d < 1024; d <<= 1) {
        int v = (t >= d) ? buf[t - d] : 0; __syncthreads();
        buf[t] += v; __syncthreads();
    }
    int excl = (t == 0) ? 0 : buf[t - 1];
    if (2 * t     < B) { boff[2 * t]     = excl;     bfill[2 * t]     = excl; }
    if (2 * t + 1 < B) { boff[2 * t + 1] = excl + a; bfill[2 * t + 1] = excl + a; }
    if (t == 0) boff[B] = E;
}

// route edges into bucket regions; desc = (src | dstlow<<17, w-bits)
__global__ __launch_bounds__(256) void bucket_scatter(const int* __restrict__ esrc,
                                                      const int* __restrict__ edst,
                                                      const float* __restrict__ ew,
                                                      int* __restrict__ bfill,
                                                      int2* __restrict__ binned, int E) {
    int tid = blockIdx.x * 256 + threadIdx.x;
    int stride = gridDim.x * 256;
    int n4 = E >> 2;
    for (int j = tid; j < n4; j += stride) {
        int4   s = ((const int4*)esrc)[j];
        int4   d = ((const int4*)edst)[j];
        float4 w = ((const float4*)ew)[j];
        int p;
        p = atomicAdd(&bfill[d.x >> NBSH], 1);
        binned[p] = make_int2(s.x | ((d.x & (NPB - 1)) << 17), __float_as_int(w.x));
        p = atomicAdd(&bfill[d.y >> NBSH], 1);
        binned[p] = make_int2(s.y | ((d.y & (NPB - 1)) << 17), __float_as_int(w.y));
        p = atomicAdd(&bfill[d.z >> NBSH], 1);
        binned[p] = make_int2(s.z | ((d.z & (NPB - 1)) << 17), __float_as_int(w.z));
        p = atomicAdd(&bfill[d.w >> NBSH], 1);
        binned[p] = make_int2(s.w | ((d.w & (NPB - 1)) << 17), __float_as_int(w.w));
    }
    for (int j = (n4 << 2) + tid; j < E; j += stride) {
        int dd = edst[j];
        int p = atomicAdd(&bfill[dd >> NBSH], 1);
        binned[p] = make_int2(esrc[j] | ((dd & (NPB - 1)) << 17), __float_as_int(ew[j]));
    }
}

// one block per bucket: 64-node x 128-float accumulator in LDS; fused residual.
// 16-edge batches per wave: descs fetched wide then broadcast to SGPRs via
// readlane; row loads are saddr-form, all issued before a sched_barrier so
// they stay in flight together; next batch's descs prefetched under atomics.
template<bool BF16>
__global__ __launch_bounds__(512) void bucket_gather(const uint* __restrict__ xb,
                                                     const float* __restrict__ x,
                                                     const int* __restrict__ boff,
                                                     const int2* __restrict__ binned,
                                                     float* __restrict__ out, int N) {
    __shared__ float acc[NPB * 128];   // 32 KB
    int b = blockIdx.x;
    int node0 = b << NBSH;

    for (int i = threadIdx.x; i < NPB * 32; i += 512)
        ((float4*)acc)[i] = make_float4(0.f, 0.f, 0.f, 0.f);
    __syncthreads();

    int beg = boff[b], end = boff[b + 1];
    int wid  = threadIdx.x >> 6;
    int lane = threadIdx.x & 63;
    int lane15 = lane & 15;

    int e0 = beg + wid * 16;
    int2 dd = make_int2(0, 0);
    if (e0 < end) {
        int ei = e0 + lane15; ei = (ei < end) ? ei : (end - 1);
        dd = binned[ei];
    }

    for (; e0 < end; e0 += 128) {   // 8 waves * 16 edges
        // ---- phase 1: broadcast descs to SGPRs, issue all row loads ----
        uint  pk[16];
        float va[16], vb[16];
        int   dl[16];
        float wv[16];
        #pragma unroll
        for (int u = 0; u < 16; ++u) {
            int sx = __builtin_amdgcn_readlane(dd.x, u);   // SGPR
            int wb = __builtin_amdgcn_readlane(dd.y, u);   // SGPR
            int src = sx & 0x1FFFF;
            dl[u] = (sx >> 17) & (NPB - 1);
            wv[u] = (e0 + u < end) ? __int_as_float(wb) : 0.0f;  // uniform select
            if (BF16) {
                pk[u] = xb[(size_t)src * 64 + lane];
            } else {
                va[u] = x[(size_t)src * 128 + lane];
                vb[u] = x[(size_t)src * 128 + lane + 64];
            }
        }
        // prefetch next batch's descs (issued after row loads -> waiting for
        // rows leaves this in flight)
        int e1 = e0 + 128;
        int2 ddn = make_int2(0, 0);
        if (e1 < end) {
            int ei = e1 + lane15; ei = (ei < end) ? ei : (end - 1);
            ddn = binned[ei];
        }
        __builtin_amdgcn_sched_barrier(0);
        // ---- phase 2: consume ----
        #pragma unroll
        for (int u = 0; u < 16; ++u) {
            float v0, v1;
            if (BF16) {
                v0 = __uint_as_float(pk[u] << 16);           // elem lane
                v1 = __uint_as_float(pk[u] & 0xFFFF0000u);   // elem lane+64
            } else { v0 = va[u]; v1 = vb[u]; }
            atomicAdd(&acc[dl[u] * 128 + lane],      v0 * wv[u]);
            atomicAdd(&acc[dl[u] * 128 + lane + 64], v1 * wv[u]);
        }
        dd = ddn;
    }
    __syncthreads();

    // epilogue: out = acc + x (residual), coalesced
    int nnodes = min(NPB, N - node0);
    for (int i = threadIdx.x; i < nnodes * 32; i += 512) {
        int node = node0 + (i >> 5);
        int c4   = i & 31;
        float4 r = ((const float4*)(x + (size_t)node * 128))[c4];
        float4 a = ((float4*)acc)[i];
        ((float4*)(out + (size_t)node * 128))[c4] =
            make_float4(a.x + r.x, a.y + r.y, a.z + r.z, a.w + r.w);
    }
}

// ------------------------------------------------- fallback atomic path

__global__ __launch_bounds__(256) void copy_kernel(const float4* __restrict__ src,
                                                   float4* __restrict__ dst, int n4) {
    int i = blockIdx.x * 256 + threadIdx.x;
    if (i < n4) dst[i] = src[i];
}

__global__ __launch_bounds__(256) void scatter_kernel(const float* __restrict__ x,
                                                      const int* __restrict__ esrc,
                                                      const int* __restrict__ edst,
                                                      const float* __restrict__ ew,
                                                      float* __restrict__ agg, int E) {
    int e = blockIdx.x * 8 + (threadIdx.x >> 5);
    if (e >= E) return;
    int lane = threadIdx.x & 31;
    int s = esrc[e];
    int d = edst[e];
    float w = ew[e];
    float4 v = ((const float4*)(x + (size_t)s * 128))[lane];
    float* dp = agg + (size_t)d * 128 + lane * 4;
    atomicAdd(dp + 0, v.x * w);
    atomicAdd(dp + 1, v.y * w);
    atomicAdd(dp + 2, v.z * w);
    atomicAdd(dp + 3, v.w * w);
}

// ----------------------------------------------------------------- GEMM

// out[r,:] = selu(in[r,:] @ W + b); W [128][128] row-major; in-place safe.
__global__ __launch_bounds__(256) void gemm_bias_selu(const float* __restrict__ inp,
                                                      const float* __restrict__ W,
                                                      const float* __restrict__ bias,
                                                      float* __restrict__ outp, int nrows) {
    __shared__ float sW[128 * 128];
    __shared__ float sH[32 * 128];

    float4* sW4 = (float4*)sW;
    float4* sH4 = (float4*)sH;

    for (int i = threadIdx.x; i < 128 * 32; i += 256)
        sW4[i] = ((const float4*)W)[i];

    int row0 = blockIdx.x * 32;
    for (int i = threadIdx.x; i < 32 * 32; i += 256) {
        int r = row0 + (i >> 5);
        sH4[i] = (r < nrows) ? ((const float4*)inp)[(size_t)r * 32 + (i & 31)]
                             : make_float4(0.f, 0.f, 0.f, 0.f);
    }
    __syncthreads();

    int cg = threadIdx.x & 31;
    int rg = (threadIdx.x >> 5) << 2;

    float4 acc[4];
    #pragma unroll
    for (int r = 0; r < 4; ++r) acc[r] = make_float4(0.f, 0.f, 0.f, 0.f);

    #pragma unroll 4
    for (int k4 = 0; k4 < 32; ++k4) {
        float4 w0 = sW4[(k4 * 4 + 0) * 32 + cg];
        float4 w1 = sW4[(k4 * 4 + 1) * 32 + cg];
        float4 w2 = sW4[(k4 * 4 + 2) * 32 + cg];
        float4 w3 = sW4[(k4 * 4 + 3) * 32 + cg];
        #pragma unroll
        for (int r = 0; r < 4; ++r) {
            float4 h = sH4[(rg + r) * 32 + k4];
            acc[r].x = fmaf(h.x, w0.x, fmaf(h.y, w1.x, fmaf(h.z, w2.x, fmaf(h.w, w3.x, acc[r].x))));
            acc[r].y = fmaf(h.x, w0.y, fmaf(h.y, w1.y, fmaf(h.z, w2.y, fmaf(h.w, w3.y, acc[r].y))));
            acc[r].z = fmaf(h.x, w0.z, fmaf(h.y, w1.z, fmaf(h.z, w2.z, fmaf(h.w, w3.z, acc[r].z))));
            acc[r].w = fmaf(h.x, w0.w, fmaf(h.y, w1.w, fmaf(h.z, w2.w, fmaf(h.w, w3.w, acc[r].w))));
        }
    }

    float4 bv = ((const float4*)bias)[cg];
    #pragma unroll
    for (int r = 0; r < 4; ++r) {
        int row = row0 + rg + r;
        if (row < nrows) {
            float4 o;
            o.x = selu_f(acc[r].x + bv.x);
            o.y = selu_f(acc[r].y + bv.y);
            o.z = selu_f(acc[r].z + bv.z);
            o.w = selu_f(acc[r].w + bv.w);
            ((float4*)outp)[(size_t)row * 32 + cg] = o;
        }
    }
}

// ---------------------------------------------------------------- launch

extern "C" void kernel_launch(void* const* d_in, const int* in_sizes, int n_in,
                              void* d_out, int out_size, void* d_ws, size_t ws_size,
                              hipStream_t stream) {
    (void)n_in; (void)out_size;
    const float* x    = (const float*)d_in[0];
    const int*   esrc = (const int*)  d_in[1];
    const int*   edst = (const int*)  d_in[2];
    const float* ew   = (const float*)d_in[3];
    const float* W1   = (const float*)d_in[4];
    const float* b1   = (const float*)d_in[5];
    const float* W2   = (const float*)d_in[6];
    const float* b2   = (const float*)d_in[7];
    float* out = (float*)d_out;

    int N = in_sizes[0] / 128;
    int E = in_sizes[1];
    int B = (N + NPB - 1) >> NBSH;

    // ws layout: bcnt(B) | boff(B+1) | bfill(B) | [align16] xb(N*128*2B) | binned(E*8B)
    size_t hdr   = ((size_t)(3 * B + 1) * 4 + 15) & ~(size_t)15;
    size_t xb_b  = (size_t)N * 256;
    size_t bin_b = (size_t)E * 8;
    size_t need_bf16 = hdr + xb_b + bin_b;
    size_t need_f32  = hdr + bin_b;

    bool use_bf16 = (ws_size >= need_bf16);
    bool use_csr  = (B <= 2048) && (ws_size >= need_f32) && (N <= 131072);

    if (use_csr) {
        int*  bcnt  = (int*)d_ws;
        int*  boff  = bcnt + B;
        int*  bfill = boff + B + 1;
        uint* xb    = (uint*)((char*)d_ws + hdr);
        int2* binned = (int2*)((char*)d_ws + hdr + (use_bf16 ? xb_b : 0));

        hipMemsetAsync(bcnt, 0, (size_t)B * 4, stream);

        if (use_bf16) {
            int total = N * 64;
            to_bf16<<<(total + 255) / 256, 256, 0, stream>>>(x, xb, total);
        }

        int hb = (E / 4 + 255) / 256; if (hb > 2048) hb = 2048;
        bucket_hist<<<hb, 256, 0, stream>>>(edst, bcnt, E, B);
        bucket_scan<<<1, 1024, 0, stream>>>(bcnt, boff, bfill, B, E);
        bucket_scatter<<<hb, 256, 0, stream>>>(esrc, edst, ew, bfill, binned, E);

        if (use_bf16)
            bucket_gather<true><<<B, 512, 0, stream>>>(xb, x, boff, binned, out, N);
        else
            bucket_gather<false><<<B, 512, 0, stream>>>(xb, x, boff, binned, out, N);
    } else {
        int n4 = N * 32;
        copy_kernel<<<(n4 + 255) / 256, 256, 0, stream>>>((const float4*)x, (float4*)out, n4);
        scatter_kernel<<<(E + 7) / 8, 256, 0, stream>>>(x, esrc, edst, ew, out, E);
    }

    // ---- dense layers, in place ----
    int gblocks = (N + 31) / 32;
    gemm_bias_selu<<<gblocks, 256, 0, stream>>>(out, W1, b1, out, N);
    gemm_bias_selu<<<gblocks, 256, 0, stream>>>(out, W2, b2, out, N);
}

// Round 7
// 899.974 us; speedup vs baseline: 3.3893x; 3.3893x over previous
//
#include <hip/hip_runtime.h>
#include <hip/hip_bf16.h>

#define SELU_LAM   1.0507009873554805f
#define SELU_ALPHA 1.6732632423543772f

// 64 nodes per bucket
#define NBSH 6
#define NPB  64
#define RCAP 6144   // refine LDS stage capacity (avg bucket ~2048 edges)

__device__ __forceinline__ float selu_f(float v) {
    return v > 0.0f ? SELU_LAM * v
                    : (SELU_LAM * SELU_ALPHA) * (expf(v) - 1.0f);
}

__device__ __forceinline__ unsigned bf16r(float f) {   // RNE f32->bf16 bits
    unsigned u = __float_as_uint(f);
    return (u + 0x7FFFu + ((u >> 16) & 1u)) >> 16;
}

// ------------------------------------------- x -> bf16, deinterleaved pairs
// xb[row*64 + l] = bf16(x[row*128 + l]) | bf16(x[row*128 + l + 64]) << 16

__global__ __launch_bounds__(256) void to_bf16(const float* __restrict__ x,
                                               uint* __restrict__ xb, int total) {
    int i = blockIdx.x * 256 + threadIdx.x;   // one uint each; total = N*64
    if (i >= total) return;
    int row = i >> 6, l = i & 63;
    float a = x[(size_t)row * 128 + l];
    float b = x[(size_t)row * 128 + l + 64];
    xb[i] = bf16r(a) | (bf16r(b) << 16);
}

// ---------------------------------------------------------------- bucketing

// LDS-privatized bucket histogram (B <= 2048)
__global__ __launch_bounds__(256) void bucket_hist(const int* __restrict__ edst,
                                                   int* __restrict__ bcnt, int E, int B) {
    __shared__ int lc[2048];
    for (int i = threadIdx.x; i < B; i += 256) lc[i] = 0;
    __syncthreads();
    int tid = blockIdx.x * 256 + threadIdx.x;
    int stride = gridDim.x * 256;
    int n4 = E >> 2;
    for (int j = tid; j < n4; j += stride) {
        int4 d = ((const int4*)edst)[j];
        atomicAdd(&lc[d.x >> NBSH], 1);
        atomicAdd(&lc[d.y >> NBSH], 1);
        atomicAdd(&lc[d.z >> NBSH], 1);
        atomicAdd(&lc[d.w >> NBSH], 1);
    }
    for (int j = (n4 << 2) + tid; j < E; j += stride) atomicAdd(&lc[edst[j] >> NBSH], 1);
    __syncthreads();
    for (int i = threadIdx.x; i < B; i += 256) if (lc[i]) atomicAdd(&bcnt[i], lc[i]);
}

// single-block exclusive scan of bucket counts (B <= 2048)
__global__ __launch_bounds__(1024) void bucket_scan(const int* __restrict__ bcnt,
                                                    int* __restrict__ boff,
                                                    int* __restrict__ bfill, int B, int E) {
    __shared__ int buf[1024];
    int t = threadIdx.x;
    int a = (2 * t     < B) ? bcnt[2 * t]     : 0;
    int b = (2 * t + 1 < B) ? bcnt[2 * t + 1] : 0;
    buf[t] = a + b; __syncthreads();
    for (int d = 1; d < 1024; d <<= 1) {
        int v = (t >= d) ? buf[t - d] : 0; __syncthreads();
        buf[t] += v; __syncthreads();
    }
    int excl = (t == 0) ? 0 : buf[t - 1];
    if (2 * t     < B) { boff[2 * t]     = excl;     bfill[2 * t]     = excl; }
    if (2 * t + 1 < B) { boff[2 * t + 1] = excl + a; bfill[2 * t + 1] = excl + a; }
    if (t == 0) boff[B] = E;
}

// route edges into bucket regions; desc = (src | dstlow<<17, w-bits)
__global__ __launch_bounds__(256) void bucket_scatter(const int* __restrict__ esrc,
                                                      const int* __restrict__ edst,
                                                      const float* __restrict__ ew,
                                                      int* __restrict__ bfill,
                                                      int2* __restrict__ binned, int E) {
    int tid = blockIdx.x * 256 + threadIdx.x;
    int stride = gridDim.x * 256;
    int n4 = E >> 2;
    for (int j = tid; j < n4; j += stride) {
        int4   s = ((const int4*)esrc)[j];
        int4   d = ((const int4*)edst)[j];
        float4 w = ((const float4*)ew)[j];
        int p;
        p = atomicAdd(&bfill[d.x >> NBSH], 1);
        binned[p] = make_int2(s.x | ((d.x & (NPB - 1)) << 17), __float_as_int(w.x));
        p = atomicAdd(&bfill[d.y >> NBSH], 1);
        binned[p] = make_int2(s.y | ((d.y & (NPB - 1)) << 17), __float_as_int(w.y));
        p = atomicAdd(&bfill[d.z >> NBSH], 1);
        binned[p] = make_int2(s.z | ((d.z & (NPB - 1)) << 17), __float_as_int(w.z));
        p = atomicAdd(&bfill[d.w >> NBSH], 1);
        binned[p] = make_int2(s.w | ((d.w & (NPB - 1)) << 17), __float_as_int(w.w));
    }
    for (int j = (n4 << 2) + tid; j < E; j += stride) {
        int dd = edst[j];
        int p = atomicAdd(&bfill[dd >> NBSH], 1);
        binned[p] = make_int2(esrc[j] | ((dd & (NPB - 1)) << 17), __float_as_int(ew[j]));
    }
}

// one block per bucket: sort the bucket's descs by node IN PLACE (LDS stage),
// emit per-node (beg,end) segments. Overflow buckets (> RCAP, ~impossible for
// random dst) stay unsorted with full-bucket segments; gather filters by the
// dst-low bits carried in each desc, so this is unconditionally correct.
__global__ __launch_bounds__(256) void refine_kernel(const int* __restrict__ boff,
                                                     int2* __restrict__ binned,
                                                     int2* __restrict__ nodeseg, int N) {
    __shared__ int2 stage[RCAP];        // 48 KB
    __shared__ int  cnt[NPB];
    __shared__ int  pref[NPB + 1];
    __shared__ int  fill[NPB];

    int b = blockIdx.x;
    int node0 = b << NBSH;
    int beg = boff[b], end = boff[b + 1];
    int count = end - beg;

    for (int i = threadIdx.x; i < NPB; i += 256) cnt[i] = 0;
    __syncthreads();

    if (count <= RCAP) {
        for (int i = threadIdx.x; i < count; i += 256) {
            int2 d = binned[beg + i];
            stage[i] = d;
            atomicAdd(&cnt[(d.x >> 17) & (NPB - 1)], 1);
        }
        __syncthreads();
        if (threadIdx.x == 0) {
            int run = 0;
            for (int k = 0; k < NPB; ++k) { pref[k] = run; run += cnt[k]; }
            pref[NPB] = run;
        }
        __syncthreads();
        if (threadIdx.x < NPB) {
            fill[threadIdx.x] = pref[threadIdx.x];
            int n = node0 + threadIdx.x;
            if (n < N)
                nodeseg[n] = make_int2(beg + pref[threadIdx.x],
                                       beg + pref[threadIdx.x + 1]);
        }
        __syncthreads();
        for (int i = threadIdx.x; i < count; i += 256) {
            int2 d = stage[i];
            int p = atomicAdd(&fill[(d.x >> 17) & (NPB - 1)], 1);
            binned[beg + p] = d;
        }
    } else {
        // overflow: leave unsorted; every node scans whole bucket (filtered)
        if (threadIdx.x < NPB) {
            int n = node0 + threadIdx.x;
            if (n < N) nodeseg[n] = make_int2(beg, end);
        }
    }
}

// one 64-lane wave per dst node; acc = x[node] + sum x[src]*w over segment.
// Lane l handles elements (l, l+64). Always filter by desc's dst-low bits
// (no-op multiply for sorted buckets, correct for overflow buckets).
template<bool BF16>
__global__ __launch_bounds__(256) void node_gather(const uint* __restrict__ xb,
                                                   const float* __restrict__ x,
                                                   const int2* __restrict__ nodeseg,
                                                   const int2* __restrict__ binned,
                                                   float* __restrict__ out, int N) {
    int node = blockIdx.x * 4 + (threadIdx.x >> 6);
    if (node >= N) return;
    int lane = threadIdx.x & 63;
    int2 seg = nodeseg[node];
    int beg = seg.x, end = seg.y;
    int mydl = node & (NPB - 1);

    float a0 = x[(size_t)node * 128 + lane];        // residual
    float a1 = x[(size_t)node * 128 + lane + 64];

    int e = beg;
    for (; e + 3 < end; e += 4) {
        int2 d0 = binned[e], d1 = binned[e + 1], d2 = binned[e + 2], d3 = binned[e + 3];
        float w0 = (((d0.x >> 17) & (NPB - 1)) == mydl) ? __int_as_float(d0.y) : 0.0f;
        float w1 = (((d1.x >> 17) & (NPB - 1)) == mydl) ? __int_as_float(d1.y) : 0.0f;
        float w2 = (((d2.x >> 17) & (NPB - 1)) == mydl) ? __int_as_float(d2.y) : 0.0f;
        float w3 = (((d3.x >> 17) & (NPB - 1)) == mydl) ? __int_as_float(d3.y) : 0.0f;
        if (BF16) {
            uint p0 = xb[(size_t)(d0.x & 0x1FFFF) * 64 + lane];
            uint p1 = xb[(size_t)(d1.x & 0x1FFFF) * 64 + lane];
            uint p2 = xb[(size_t)(d2.x & 0x1FFFF) * 64 + lane];
            uint p3 = xb[(size_t)(d3.x & 0x1FFFF) * 64 + lane];
            a0 = fmaf(__uint_as_float(p0 << 16), w0, a0);
            a1 = fmaf(__uint_as_float(p0 & 0xFFFF0000u), w0, a1);
            a0 = fmaf(__uint_as_float(p1 << 16), w1, a0);
            a1 = fmaf(__uint_as_float(p1 & 0xFFFF0000u), w1, a1);
            a0 = fmaf(__uint_as_float(p2 << 16), w2, a0);
            a1 = fmaf(__uint_as_float(p2 & 0xFFFF0000u), w2, a1);
            a0 = fmaf(__uint_as_float(p3 << 16), w3, a0);
            a1 = fmaf(__uint_as_float(p3 & 0xFFFF0000u), w3, a1);
        } else {
            float u0 = x[(size_t)(d0.x & 0x1FFFF) * 128 + lane];
            float v0 = x[(size_t)(d0.x & 0x1FFFF) * 128 + lane + 64];
            float u1 = x[(size_t)(d1.x & 0x1FFFF) * 128 + lane];
            float v1 = x[(size_t)(d1.x & 0x1FFFF) * 128 + lane + 64];
            float u2 = x[(size_t)(d2.x & 0x1FFFF) * 128 + lane];
            float v2 = x[(size_t)(d2.x & 0x1FFFF) * 128 + lane + 64];
            float u3 = x[(size_t)(d3.x & 0x1FFFF) * 128 + lane];
            float v3 = x[(size_t)(d3.x & 0x1FFFF) * 128 + lane + 64];
            a0 = fmaf(u0, w0, a0); a1 = fmaf(v0, w0, a1);
            a0 = fmaf(u1, w1, a0); a1 = fmaf(v1, w1, a1);
            a0 = fmaf(u2, w2, a0); a1 = fmaf(v2, w2, a1);
            a0 = fmaf(u3, w3, a0); a1 = fmaf(v3, w3, a1);
        }
    }
    for (; e < end; ++e) {
        int2 d0 = binned[e];
        float w0 = (((d0.x >> 17) & (NPB - 1)) == mydl) ? __int_as_float(d0.y) : 0.0f;
        if (BF16) {
            uint p0 = xb[(size_t)(d0.x & 0x1FFFF) * 64 + lane];
            a0 = fmaf(__uint_as_float(p0 << 16), w0, a0);
            a1 = fmaf(__uint_as_float(p0 & 0xFFFF0000u), w0, a1);
        } else {
            float u0 = x[(size_t)(d0.x & 0x1FFFF) * 128 + lane];
            float v0 = x[(size_t)(d0.x & 0x1FFFF) * 128 + lane + 64];
            a0 = fmaf(u0, w0, a0); a1 = fmaf(v0, w0, a1);
        }
    }

    out[(size_t)node * 128 + lane]      = a0;
    out[(size_t)node * 128 + lane + 64] = a1;
}

// ------------------------------------------------- fallback atomic path

__global__ __launch_bounds__(256) void copy_kernel(const float4* __restrict__ src,
                                                   float4* __restrict__ dst, int n4) {
    int i = blockIdx.x * 256 + threadIdx.x;
    if (i < n4) dst[i] = src[i];
}

__global__ __launch_bounds__(256) void scatter_kernel(const float* __restrict__ x,
                                                      const int* __restrict__ esrc,
                                                      const int* __restrict__ edst,
                                                      const float* __restrict__ ew,
                                                      float* __restrict__ agg, int E) {
    int e = blockIdx.x * 8 + (threadIdx.x >> 5);
    if (e >= E) return;
    int lane = threadIdx.x & 31;
    int s = esrc[e];
    int d = edst[e];
    float w = ew[e];
    float4 v = ((const float4*)(x + (size_t)s * 128))[lane];
    float* dp = agg + (size_t)d * 128 + lane * 4;
    atomicAdd(dp + 0, v.x * w);
    atomicAdd(dp + 1, v.y * w);
    atomicAdd(dp + 2, v.z * w);
    atomicAdd(dp + 3, v.w * w);
}

// ----------------------------------------------------------------- GEMM

// out[r,:] = selu(in[r,:] @ W + b); W [128][128] row-major; in-place safe.
__global__ __launch_bounds__(256) void gemm_bias_selu(const float* __restrict__ inp,
                                                      const float* __restrict__ W,
                                                      const float* __restrict__ bias,
                                                      float* __restrict__ outp, int nrows) {
    __shared__ float sW[128 * 128];
    __shared__ float sH[32 * 128];

    float4* sW4 = (float4*)sW;
    float4* sH4 = (float4*)sH;

    for (int i = threadIdx.x; i < 128 * 32; i += 256)
        sW4[i] = ((const float4*)W)[i];

    int row0 = blockIdx.x * 32;
    for (int i = threadIdx.x; i < 32 * 32; i += 256) {
        int r = row0 + (i >> 5);
        sH4[i] = (r < nrows) ? ((const float4*)inp)[(size_t)r * 32 + (i & 31)]
                             : make_float4(0.f, 0.f, 0.f, 0.f);
    }
    __syncthreads();

    int cg = threadIdx.x & 31;
    int rg = (threadIdx.x >> 5) << 2;

    float4 acc[4];
    #pragma unroll
    for (int r = 0; r < 4; ++r) acc[r] = make_float4(0.f, 0.f, 0.f, 0.f);

    #pragma unroll 4
    for (int k4 = 0; k4 < 32; ++k4) {
        float4 w0 = sW4[(k4 * 4 + 0) * 32 + cg];
        float4 w1 = sW4[(k4 * 4 + 1) * 32 + cg];
        float4 w2 = sW4[(k4 * 4 + 2) * 32 + cg];
        float4 w3 = sW4[(k4 * 4 + 3) * 32 + cg];
        #pragma unroll
        for (int r = 0; r < 4; ++r) {
            float4 h = sH4[(rg + r) * 32 + k4];
            acc[r].x = fmaf(h.x, w0.x, fmaf(h.y, w1.x, fmaf(h.z, w2.x, fmaf(h.w, w3.x, acc[r].x))));
            acc[r].y = fmaf(h.x, w0.y, fmaf(h.y, w1.y, fmaf(h.z, w2.y, fmaf(h.w, w3.y, acc[r].y))));
            acc[r].z = fmaf(h.x, w0.z, fmaf(h.y, w1.z, fmaf(h.z, w2.z, fmaf(h.w, w3.z, acc[r].z))));
            acc[r].w = fmaf(h.x, w0.w, fmaf(h.y, w1.w, fmaf(h.z, w2.w, fmaf(h.w, w3.w, acc[r].w))));
        }
    }

    float4 bv = ((const float4*)bias)[cg];
    #pragma unroll
    for (int r = 0; r < 4; ++r) {
        int row = row0 + rg + r;
        if (row < nrows) {
            float4 o;
            o.x = selu_f(acc[r].x + bv.x);
            o.y = selu_f(acc[r].y + bv.y);
            o.z = selu_f(acc[r].z + bv.z);
            o.w = selu_f(acc[r].w + bv.w);
            ((float4*)outp)[(size_t)row * 32 + cg] = o;
        }
    }
}

// ---------------------------------------------------------------- launch

extern "C" void kernel_launch(void* const* d_in, const int* in_sizes, int n_in,
                              void* d_out, int out_size, void* d_ws, size_t ws_size,
                              hipStream_t stream) {
    (void)n_in; (void)out_size;
    const float* x    = (const float*)d_in[0];
    const int*   esrc = (const int*)  d_in[1];
    const int*   edst = (const int*)  d_in[2];
    const float* ew   = (const float*)d_in[3];
    const float* W1   = (const float*)d_in[4];
    const float* b1   = (const float*)d_in[5];
    const float* W2   = (const float*)d_in[6];
    const float* b2   = (const float*)d_in[7];
    float* out = (float*)d_out;

    int N = in_sizes[0] / 128;
    int E = in_sizes[1];
    int B = (N + NPB - 1) >> NBSH;

    // ws layout: bcnt(B) | boff(B+1) | bfill(B) | [align16] nodeseg(N int2) |
    //            xb(N*64 uint) | binned(E int2)
    size_t hdr   = ((size_t)(3 * B + 1) * 4 + 15) & ~(size_t)15;
    size_t seg_b = (size_t)N * 8;
    size_t xb_b  = (size_t)N * 256;
    size_t bin_b = (size_t)E * 8;
    size_t need_bf16 = hdr + seg_b + xb_b + bin_b;
    size_t need_f32  = hdr + seg_b + bin_b;

    bool use_bf16 = (ws_size >= need_bf16);
    bool use_csr  = (B <= 2048) && (ws_size >= need_f32) && (N <= 131072);

    if (use_csr) {
        int*  bcnt    = (int*)d_ws;
        int*  boff    = bcnt + B;
        int*  bfill   = boff + B + 1;
        int2* nodeseg = (int2*)((char*)d_ws + hdr);
        uint* xb      = (uint*)((char*)d_ws + hdr + seg_b);
        int2* binned  = (int2*)((char*)d_ws + hdr + seg_b + (use_bf16 ? xb_b : 0));

        hipMemsetAsync(bcnt, 0, (size_t)B * 4, stream);

        if (use_bf16) {
            int total = N * 64;
            to_bf16<<<(total + 255) / 256, 256, 0, stream>>>(x, xb, total);
        }

        int hb = (E / 4 + 255) / 256; if (hb > 2048) hb = 2048;
        bucket_hist<<<hb, 256, 0, stream>>>(edst, bcnt, E, B);
        bucket_scan<<<1, 1024, 0, stream>>>(bcnt, boff, bfill, B, E);
        bucket_scatter<<<hb, 256, 0, stream>>>(esrc, edst, ew, bfill, binned, E);
        refine_kernel<<<B, 256, 0, stream>>>(boff, binned, nodeseg, N);

        int gb = (N + 3) / 4;
        if (use_bf16)
            node_gather<true><<<gb, 256, 0, stream>>>(xb, x, nodeseg, binned, out, N);
        else
            node_gather<false><<<gb, 256, 0, stream>>>(xb, x, nodeseg, binned, out, N);
    } else {
        int n4 = N * 32;
        copy_kernel<<<(n4 + 255) / 256, 256, 0, stream>>>((const float4*)x, (float4*)out, n4);
        scatter_kernel<<<(E + 7) / 8, 256, 0, stream>>>(x, esrc, edst, ew, out, E);
    }

    // ---- dense layers, in place ----
    int gblocks = (N + 31) / 32;
    gemm_bias_selu<<<gblocks, 256, 0, stream>>>(out, W1, b1, out, N);
    gemm_bias_selu<<<gblocks, 256, 0, stream>>>(out, W2, b2, out, N);
}

// Round 8
// 465.035 us; speedup vs baseline: 6.5592x; 1.9353x over previous
//
#include <hip/hip_runtime.h>
#include <hip/hip_bf16.h>

#define SELU_LAM   1.0507009873554805f
#define SELU_ALPHA 1.6732632423543772f

// 64 nodes per bucket
#define NBSH 6
#define NPB  64
#define RCAP 6144    // refine LDS stage capacity (avg bucket ~2048 edges)
#define SCHUNK 16384 // edges per chunk in chunk_scatter

__device__ __forceinline__ float selu_f(float v) {
    return v > 0.0f ? SELU_LAM * v
                    : (SELU_LAM * SELU_ALPHA) * (expf(v) - 1.0f);
}

__device__ __forceinline__ unsigned bf16r(float f) {   // RNE f32->bf16 bits
    unsigned u = __float_as_uint(f);
    return (u + 0x7FFFu + ((u >> 16) & 1u)) >> 16;
}

// ------------------------------------------- x -> bf16, deinterleaved pairs
// xb[row*64 + l] = bf16(x[row*128 + l]) | bf16(x[row*128 + l + 64]) << 16

__global__ __launch_bounds__(256) void to_bf16(const float* __restrict__ x,
                                               uint* __restrict__ xb, int total) {
    int i = blockIdx.x * 256 + threadIdx.x;   // one uint each; total = N*64
    if (i >= total) return;
    int row = i >> 6, l = i & 63;
    float a = x[(size_t)row * 128 + l];
    float b = x[(size_t)row * 128 + l + 64];
    xb[i] = bf16r(a) | (bf16r(b) << 16);
}

// ---------------------------------------------------------------- bucketing

// LDS-privatized bucket histogram (B <= 2048)
__global__ __launch_bounds__(256) void bucket_hist(const int* __restrict__ edst,
                                                   int* __restrict__ bcnt, int E, int B) {
    __shared__ int lc[2048];
    for (int i = threadIdx.x; i < B; i += 256) lc[i] = 0;
    __syncthreads();
    int tid = blockIdx.x * 256 + threadIdx.x;
    int stride = gridDim.x * 256;
    int n4 = E >> 2;
    for (int j = tid; j < n4; j += stride) {
        int4 d = ((const int4*)edst)[j];
        atomicAdd(&lc[d.x >> NBSH], 1);
        atomicAdd(&lc[d.y >> NBSH], 1);
        atomicAdd(&lc[d.z >> NBSH], 1);
        atomicAdd(&lc[d.w >> NBSH], 1);
    }
    for (int j = (n4 << 2) + tid; j < E; j += stride) atomicAdd(&lc[edst[j] >> NBSH], 1);
    __syncthreads();
    for (int i = threadIdx.x; i < B; i += 256) if (lc[i]) atomicAdd(&bcnt[i], lc[i]);
}

// single-block exclusive scan of bucket counts (B <= 2048)
__global__ __launch_bounds__(1024) void bucket_scan(const int* __restrict__ bcnt,
                                                    int* __restrict__ boff,
                                                    int* __restrict__ bfill, int B, int E) {
    __shared__ int buf[1024];
    int t = threadIdx.x;
    int a = (2 * t     < B) ? bcnt[2 * t]     : 0;
    int b = (2 * t + 1 < B) ? bcnt[2 * t + 1] : 0;
    buf[t] = a + b; __syncthreads();
    for (int d = 1; d < 1024; d <<= 1) {
        int v = (t >= d) ? buf[t - d] : 0; __syncthreads();
        buf[t] += v; __syncthreads();
    }
    int excl = (t == 0) ? 0 : buf[t - 1];
    if (2 * t     < B) { boff[2 * t]     = excl;     bfill[2 * t]     = excl; }
    if (2 * t + 1 < B) { boff[2 * t + 1] = excl + a; bfill[2 * t + 1] = excl + a; }
    if (t == 0) boff[B] = E;
}

// Block-batched binning: each block counting-sorts a 16K-edge chunk.
// Pass A: LDS per-bucket counts. Claim: ONE global atomicAdd per (block,
// bucket). Pass B: re-read chunk (L2-hot), write each bucket's edges as a
// contiguous run -> full-line writes from a single wave set, no cross-XCD
// line sharing. desc = (src | dstlow<<17, w-bits)
__global__ __launch_bounds__(512) void chunk_scatter(const int* __restrict__ esrc,
                                                     const int* __restrict__ edst,
                                                     const float* __restrict__ ew,
                                                     int* __restrict__ bfill,
                                                     int2* __restrict__ binned,
                                                     int E, int B) {
    __shared__ int cnt[2048];
    __shared__ int base[2048];
    int tid = threadIdx.x;
    int nchunks = (E + SCHUNK - 1) / SCHUNK;

    for (int c = blockIdx.x; c < nchunks; c += gridDim.x) {
        int lo = c * SCHUNK;
        int hi = min(lo + SCHUNK, E);
        int full = lo + ((hi - lo) & ~3);

        for (int i = tid; i < B; i += 512) cnt[i] = 0;
        __syncthreads();

        // pass A: count
        for (int i = lo + tid * 4; i < full; i += 2048) {
            int4 d = *(const int4*)(edst + i);
            atomicAdd(&cnt[d.x >> NBSH], 1);
            atomicAdd(&cnt[d.y >> NBSH], 1);
            atomicAdd(&cnt[d.z >> NBSH], 1);
            atomicAdd(&cnt[d.w >> NBSH], 1);
        }
        for (int i = full + tid; i < hi; i += 512) atomicAdd(&cnt[edst[i] >> NBSH], 1);
        __syncthreads();

        // claim: one atomic per touched bucket
        for (int i = tid; i < B; i += 512) {
            int c0 = cnt[i];
            base[i] = c0 ? atomicAdd(&bfill[i], c0) : 0;
            cnt[i] = 0;                       // reuse as local fill
        }
        __syncthreads();

        // pass B: write contiguous runs
        for (int i = lo + tid * 4; i < full; i += 2048) {
            int4   s = *(const int4*)(esrc + i);
            int4   d = *(const int4*)(edst + i);
            float4 w = *(const float4*)(ew + i);
            int b0 = d.x >> NBSH, b1 = d.y >> NBSH, b2 = d.z >> NBSH, b3 = d.w >> NBSH;
            int p;
            p = base[b0] + atomicAdd(&cnt[b0], 1);
            binned[p] = make_int2(s.x | ((d.x & (NPB - 1)) << 17), __float_as_int(w.x));
            p = base[b1] + atomicAdd(&cnt[b1], 1);
            binned[p] = make_int2(s.y | ((d.y & (NPB - 1)) << 17), __float_as_int(w.y));
            p = base[b2] + atomicAdd(&cnt[b2], 1);
            binned[p] = make_int2(s.z | ((d.z & (NPB - 1)) << 17), __float_as_int(w.z));
            p = base[b3] + atomicAdd(&cnt[b3], 1);
            binned[p] = make_int2(s.w | ((d.w & (NPB - 1)) << 17), __float_as_int(w.w));
        }
        for (int i = full + tid; i < hi; i += 512) {
            int dd = edst[i];
            int b = dd >> NBSH;
            int p = base[b] + atomicAdd(&cnt[b], 1);
            binned[p] = make_int2(esrc[i] | ((dd & (NPB - 1)) << 17), __float_as_int(ew[i]));
        }
        __syncthreads();
    }
}

// one block per bucket: sort the bucket's descs by node IN PLACE (LDS stage),
// emit per-node (beg,end) segments. Overflow buckets (> RCAP, ~impossible for
// random dst) stay unsorted with full-bucket segments; gather filters by the
// dst-low bits carried in each desc, so this is unconditionally correct.
__global__ __launch_bounds__(256) void refine_kernel(const int* __restrict__ boff,
                                                     int2* __restrict__ binned,
                                                     int2* __restrict__ nodeseg, int N) {
    __shared__ int2 stage[RCAP];        // 48 KB
    __shared__ int  cnt[NPB];
    __shared__ int  pref[NPB + 1];
    __shared__ int  fill[NPB];

    int b = blockIdx.x;
    int node0 = b << NBSH;
    int beg = boff[b], end = boff[b + 1];
    int count = end - beg;

    for (int i = threadIdx.x; i < NPB; i += 256) cnt[i] = 0;
    __syncthreads();

    if (count <= RCAP) {
        for (int i = threadIdx.x; i < count; i += 256) {
            int2 d = binned[beg + i];
            stage[i] = d;
            atomicAdd(&cnt[(d.x >> 17) & (NPB - 1)], 1);
        }
        __syncthreads();
        if (threadIdx.x == 0) {
            int run = 0;
            for (int k = 0; k < NPB; ++k) { pref[k] = run; run += cnt[k]; }
            pref[NPB] = run;
        }
        __syncthreads();
        if (threadIdx.x < NPB) {
            fill[threadIdx.x] = pref[threadIdx.x];
            int n = node0 + threadIdx.x;
            if (n < N)
                nodeseg[n] = make_int2(beg + pref[threadIdx.x],
                                       beg + pref[threadIdx.x + 1]);
        }
        __syncthreads();
        for (int i = threadIdx.x; i < count; i += 256) {
            int2 d = stage[i];
            int p = atomicAdd(&fill[(d.x >> 17) & (NPB - 1)], 1);
            binned[beg + p] = d;
        }
    } else {
        // overflow: leave unsorted; every node scans whole bucket (filtered)
        if (threadIdx.x < NPB) {
            int n = node0 + threadIdx.x;
            if (n < N) nodeseg[n] = make_int2(beg, end);
        }
    }
}

// one 64-lane wave per dst node; acc = x[node] + sum x[src]*w over segment.
// Lane l handles elements (l, l+64). Always filter by desc's dst-low bits
// (no-op multiply for sorted buckets, correct for overflow buckets).
template<bool BF16>
__global__ __launch_bounds__(256) void node_gather(const uint* __restrict__ xb,
                                                   const float* __restrict__ x,
                                                   const int2* __restrict__ nodeseg,
                                                   const int2* __restrict__ binned,
                                                   float* __restrict__ out, int N) {
    int node = blockIdx.x * 4 + (threadIdx.x >> 6);
    if (node >= N) return;
    int lane = threadIdx.x & 63;
    int2 seg = nodeseg[node];
    int beg = seg.x, end = seg.y;
    int mydl = node & (NPB - 1);

    float a0 = x[(size_t)node * 128 + lane];        // residual
    float a1 = x[(size_t)node * 128 + lane + 64];

    int e = beg;
    for (; e + 3 < end; e += 4) {
        int2 d0 = binned[e], d1 = binned[e + 1], d2 = binned[e + 2], d3 = binned[e + 3];
        float w0 = (((d0.x >> 17) & (NPB - 1)) == mydl) ? __int_as_float(d0.y) : 0.0f;
        float w1 = (((d1.x >> 17) & (NPB - 1)) == mydl) ? __int_as_float(d1.y) : 0.0f;
        float w2 = (((d2.x >> 17) & (NPB - 1)) == mydl) ? __int_as_float(d2.y) : 0.0f;
        float w3 = (((d3.x >> 17) & (NPB - 1)) == mydl) ? __int_as_float(d3.y) : 0.0f;
        if (BF16) {
            uint p0 = xb[(size_t)(d0.x & 0x1FFFF) * 64 + lane];
            uint p1 = xb[(size_t)(d1.x & 0x1FFFF) * 64 + lane];
            uint p2 = xb[(size_t)(d2.x & 0x1FFFF) * 64 + lane];
            uint p3 = xb[(size_t)(d3.x & 0x1FFFF) * 64 + lane];
            a0 = fmaf(__uint_as_float(p0 << 16), w0, a0);
            a1 = fmaf(__uint_as_float(p0 & 0xFFFF0000u), w0, a1);
            a0 = fmaf(__uint_as_float(p1 << 16), w1, a0);
            a1 = fmaf(__uint_as_float(p1 & 0xFFFF0000u), w1, a1);
            a0 = fmaf(__uint_as_float(p2 << 16), w2, a0);
            a1 = fmaf(__uint_as_float(p2 & 0xFFFF0000u), w2, a1);
            a0 = fmaf(__uint_as_float(p3 << 16), w3, a0);
            a1 = fmaf(__uint_as_float(p3 & 0xFFFF0000u), w3, a1);
        } else {
            float u0 = x[(size_t)(d0.x & 0x1FFFF) * 128 + lane];
            float v0 = x[(size_t)(d0.x & 0x1FFFF) * 128 + lane + 64];
            float u1 = x[(size_t)(d1.x & 0x1FFFF) * 128 + lane];
            float v1 = x[(size_t)(d1.x & 0x1FFFF) * 128 + lane + 64];
            float u2 = x[(size_t)(d2.x & 0x1FFFF) * 128 + lane];
            float v2 = x[(size_t)(d2.x & 0x1FFFF) * 128 + lane + 64];
            float u3 = x[(size_t)(d3.x & 0x1FFFF) * 128 + lane];
            float v3 = x[(size_t)(d3.x & 0x1FFFF) * 128 + lane + 64];
            a0 = fmaf(u0, w0, a0); a1 = fmaf(v0, w0, a1);
            a0 = fmaf(u1, w1, a0); a1 = fmaf(v1, w1, a1);
            a0 = fmaf(u2, w2, a0); a1 = fmaf(v2, w2, a1);
            a0 = fmaf(u3, w3, a0); a1 = fmaf(v3, w3, a1);
        }
    }
    for (; e < end; ++e) {
        int2 d0 = binned[e];
        float w0 = (((d0.x >> 17) & (NPB - 1)) == mydl) ? __int_as_float(d0.y) : 0.0f;
        if (BF16) {
            uint p0 = xb[(size_t)(d0.x & 0x1FFFF) * 64 + lane];
            a0 = fmaf(__uint_as_float(p0 << 16), w0, a0);
            a1 = fmaf(__uint_as_float(p0 & 0xFFFF0000u), w0, a1);
        } else {
            float u0 = x[(size_t)(d0.x & 0x1FFFF) * 128 + lane];
            float v0 = x[(size_t)(d0.x & 0x1FFFF) * 128 + lane + 64];
            a0 = fmaf(u0, w0, a0); a1 = fmaf(v0, w0, a1);
        }
    }

    out[(size_t)node * 128 + lane]      = a0;
    out[(size_t)node * 128 + lane + 64] = a1;
}

// ------------------------------------------------- fallback atomic path

__global__ __launch_bounds__(256) void copy_kernel(const float4* __restrict__ src,
                                                   float4* __restrict__ dst, int n4) {
    int i = blockIdx.x * 256 + threadIdx.x;
    if (i < n4) dst[i] = src[i];
}

__global__ __launch_bounds__(256) void scatter_kernel(const float* __restrict__ x,
                                                      const int* __restrict__ esrc,
                                                      const int* __restrict__ edst,
                                                      const float* __restrict__ ew,
                                                      float* __restrict__ agg, int E) {
    int e = blockIdx.x * 8 + (threadIdx.x >> 5);
    if (e >= E) return;
    int lane = threadIdx.x & 31;
    int s = esrc[e];
    int d = edst[e];
    float w = ew[e];
    float4 v = ((const float4*)(x + (size_t)s * 128))[lane];
    float* dp = agg + (size_t)d * 128 + lane * 4;
    atomicAdd(dp + 0, v.x * w);
    atomicAdd(dp + 1, v.y * w);
    atomicAdd(dp + 2, v.z * w);
    atomicAdd(dp + 3, v.w * w);
}

// ----------------------------------------------------------------- GEMM

// out[r,:] = selu(in[r,:] @ W + b); W [128][128] row-major; in-place safe.
__global__ __launch_bounds__(256) void gemm_bias_selu(const float* __restrict__ inp,
                                                      const float* __restrict__ W,
                                                      const float* __restrict__ bias,
                                                      float* __restrict__ outp, int nrows) {
    __shared__ float sW[128 * 128];
    __shared__ float sH[32 * 128];

    float4* sW4 = (float4*)sW;
    float4* sH4 = (float4*)sH;

    for (int i = threadIdx.x; i < 128 * 32; i += 256)
        sW4[i] = ((const float4*)W)[i];

    int row0 = blockIdx.x * 32;
    for (int i = threadIdx.x; i < 32 * 32; i += 256) {
        int r = row0 + (i >> 5);
        sH4[i] = (r < nrows) ? ((const float4*)inp)[(size_t)r * 32 + (i & 31)]
                             : make_float4(0.f, 0.f, 0.f, 0.f);
    }
    __syncthreads();

    int cg = threadIdx.x & 31;
    int rg = (threadIdx.x >> 5) << 2;

    float4 acc[4];
    #pragma unroll
    for (int r = 0; r < 4; ++r) acc[r] = make_float4(0.f, 0.f, 0.f, 0.f);

    #pragma unroll 4
    for (int k4 = 0; k4 < 32; ++k4) {
        float4 w0 = sW4[(k4 * 4 + 0) * 32 + cg];
        float4 w1 = sW4[(k4 * 4 + 1) * 32 + cg];
        float4 w2 = sW4[(k4 * 4 + 2) * 32 + cg];
        float4 w3 = sW4[(k4 * 4 + 3) * 32 + cg];
        #pragma unroll
        for (int r = 0; r < 4; ++r) {
            float4 h = sH4[(rg + r) * 32 + k4];
            acc[r].x = fmaf(h.x, w0.x, fmaf(h.y, w1.x, fmaf(h.z, w2.x, fmaf(h.w, w3.x, acc[r].x))));
            acc[r].y = fmaf(h.x, w0.y, fmaf(h.y, w1.y, fmaf(h.z, w2.y, fmaf(h.w, w3.y, acc[r].y))));
            acc[r].z = fmaf(h.x, w0.z, fmaf(h.y, w1.z, fmaf(h.z, w2.z, fmaf(h.w, w3.z, acc[r].z))));
            acc[r].w = fmaf(h.x, w0.w, fmaf(h.y, w1.w, fmaf(h.z, w2.w, fmaf(h.w, w3.w, acc[r].w))));
        }
    }

    float4 bv = ((const float4*)bias)[cg];
    #pragma unroll
    for (int r = 0; r < 4; ++r) {
        int row = row0 + rg + r;
        if (row < nrows) {
            float4 o;
            o.x = selu_f(acc[r].x + bv.x);
            o.y = selu_f(acc[r].y + bv.y);
            o.z = selu_f(acc[r].z + bv.z);
            o.w = selu_f(acc[r].w + bv.w);
            ((float4*)outp)[(size_t)row * 32 + cg] = o;
        }
    }
}

// ---------------------------------------------------------------- launch

extern "C" void kernel_launch(void* const* d_in, const int* in_sizes, int n_in,
                              void* d_out, int out_size, void* d_ws, size_t ws_size,
                              hipStream_t stream) {
    (void)n_in; (void)out_size;
    const float* x    = (const float*)d_in[0];
    const int*   esrc = (const int*)  d_in[1];
    const int*   edst = (const int*)  d_in[2];
    const float* ew   = (const float*)d_in[3];
    const float* W1   = (const float*)d_in[4];
    const float* b1   = (const float*)d_in[5];
    const float* W2   = (const float*)d_in[6];
    const float* b2   = (const float*)d_in[7];
    float* out = (float*)d_out;

    int N = in_sizes[0] / 128;
    int E = in_sizes[1];
    int B = (N + NPB - 1) >> NBSH;

    // ws layout: bcnt(B) | boff(B+1) | bfill(B) | [align16] nodeseg(N int2) |
    //            xb(N*64 uint) | binned(E int2)
    size_t hdr   = ((size_t)(3 * B + 1) * 4 + 15) & ~(size_t)15;
    size_t seg_b = (size_t)N * 8;
    size_t xb_b  = (size_t)N * 256;
    size_t bin_b = (size_t)E * 8;
    size_t need_bf16 = hdr + seg_b + xb_b + bin_b;
    size_t need_f32  = hdr + seg_b + bin_b;

    bool use_bf16 = (ws_size >= need_bf16);
    bool use_csr  = (B <= 2048) && (ws_size >= need_f32) && (N <= 131072);

    if (use_csr) {
        int*  bcnt    = (int*)d_ws;
        int*  boff    = bcnt + B;
        int*  bfill   = boff + B + 1;
        int2* nodeseg = (int2*)((char*)d_ws + hdr);
        uint* xb      = (uint*)((char*)d_ws + hdr + seg_b);
        int2* binned  = (int2*)((char*)d_ws + hdr + seg_b + (use_bf16 ? xb_b : 0));

        hipMemsetAsync(bcnt, 0, (size_t)B * 4, stream);

        if (use_bf16) {
            int total = N * 64;
            to_bf16<<<(total + 255) / 256, 256, 0, stream>>>(x, xb, total);
        }

        int hb = (E / 4 + 255) / 256; if (hb > 2048) hb = 2048;
        bucket_hist<<<hb, 256, 0, stream>>>(edst, bcnt, E, B);
        bucket_scan<<<1, 1024, 0, stream>>>(bcnt, boff, bfill, B, E);

        int nchunks = (E + SCHUNK - 1) / SCHUNK; if (nchunks > 2048) nchunks = 2048;
        chunk_scatter<<<nchunks, 512, 0, stream>>>(esrc, edst, ew, bfill, binned, E, B);

        refine_kernel<<<B, 256, 0, stream>>>(boff, binned, nodeseg, N);

        int gb = (N + 3) / 4;
        if (use_bf16)
            node_gather<true><<<gb, 256, 0, stream>>>(xb, x, nodeseg, binned, out, N);
        else
            node_gather<false><<<gb, 256, 0, stream>>>(xb, x, nodeseg, binned, out, N);
    } else {
        int n4 = N * 32;
        copy_kernel<<<(n4 + 255) / 256, 256, 0, stream>>>((const float4*)x, (float4*)out, n4);
        scatter_kernel<<<(E + 7) / 8, 256, 0, stream>>>(x, esrc, edst, ew, out, E);
    }

    // ---- dense layers, in place ----
    int gblocks = (N + 31) / 32;
    gemm_bias_selu<<<gblocks, 256, 0, stream>>>(out, W1, b1, out, N);
    gemm_bias_selu<<<gblocks, 256, 0, stream>>>(out, W2, b2, out, N);
}

// Round 9
// 362.057 us; speedup vs baseline: 8.4248x; 1.2844x over previous
//
#include <hip/hip_runtime.h>
#include <hip/hip_bf16.h>

#define SELU_LAM   1.0507009873554805f
#define SELU_ALPHA 1.6732632423543772f

// 64 nodes per bucket
#define NBSH 6
#define NPB  64
#define RCAP 6144    // refine LDS stage capacity (avg bucket ~2048 edges)
#define SCHUNK 16384 // edges per chunk in chunk_scatter
#define MROWS 32     // rows per block in fused MLP

typedef __attribute__((ext_vector_type(8))) short bf16x8;
typedef __attribute__((ext_vector_type(4))) float f32x4;

__device__ __forceinline__ float selu_f(float v) {
    return v > 0.0f ? SELU_LAM * v
                    : (SELU_LAM * SELU_ALPHA) * (expf(v) - 1.0f);
}

__device__ __forceinline__ unsigned bf16r(float f) {   // RNE f32->bf16 bits
    unsigned u = __float_as_uint(f);
    return (u + 0x7FFFu + ((u >> 16) & 1u)) >> 16;
}

// ------------------------------------------- x -> bf16, deinterleaved pairs
// xb[row*64 + l] = bf16(x[row*128 + l]) | bf16(x[row*128 + l + 64]) << 16

__global__ __launch_bounds__(256) void to_bf16(const float* __restrict__ x,
                                               uint* __restrict__ xb, int total) {
    int i = blockIdx.x * 256 + threadIdx.x;   // one uint each; total = N*64
    if (i >= total) return;
    int row = i >> 6, l = i & 63;
    float a = x[(size_t)row * 128 + l];
    float b = x[(size_t)row * 128 + l + 64];
    xb[i] = bf16r(a) | (bf16r(b) << 16);
}

// ---------------------------------------------------------------- bucketing

// LDS-privatized bucket histogram (B <= 2048)
__global__ __launch_bounds__(256) void bucket_hist(const int* __restrict__ edst,
                                                   int* __restrict__ bcnt, int E, int B) {
    __shared__ int lc[2048];
    for (int i = threadIdx.x; i < B; i += 256) lc[i] = 0;
    __syncthreads();
    int tid = blockIdx.x * 256 + threadIdx.x;
    int stride = gridDim.x * 256;
    int n4 = E >> 2;
    for (int j = tid; j < n4; j += stride) {
        int4 d = ((const int4*)edst)[j];
        atomicAdd(&lc[d.x >> NBSH], 1);
        atomicAdd(&lc[d.y >> NBSH], 1);
        atomicAdd(&lc[d.z >> NBSH], 1);
        atomicAdd(&lc[d.w >> NBSH], 1);
    }
    for (int j = (n4 << 2) + tid; j < E; j += stride) atomicAdd(&lc[edst[j] >> NBSH], 1);
    __syncthreads();
    for (int i = threadIdx.x; i < B; i += 256) if (lc[i]) atomicAdd(&bcnt[i], lc[i]);
}

// single-block exclusive scan of bucket counts (B <= 2048)
__global__ __launch_bounds__(1024) void bucket_scan(const int* __restrict__ bcnt,
                                                    int* __restrict__ boff,
                                                    int* __restrict__ bfill, int B, int E) {
    __shared__ int buf[1024];
    int t = threadIdx.x;
    int a = (2 * t     < B) ? bcnt[2 * t]     : 0;
    int b = (2 * t + 1 < B) ? bcnt[2 * t + 1] : 0;
    buf[t] = a + b; __syncthreads();
    for (int d = 1; d < 1024; d <<= 1) {
        int v = (t >= d) ? buf[t - d] : 0; __syncthreads();
        buf[t] += v; __syncthreads();
    }
    int excl = (t == 0) ? 0 : buf[t - 1];
    if (2 * t     < B) { boff[2 * t]     = excl;     bfill[2 * t]     = excl; }
    if (2 * t + 1 < B) { boff[2 * t + 1] = excl + a; bfill[2 * t + 1] = excl + a; }
    if (t == 0) boff[B] = E;
}

// Block-batched binning: each block counting-sorts a 16K-edge chunk.
__global__ __launch_bounds__(512) void chunk_scatter(const int* __restrict__ esrc,
                                                     const int* __restrict__ edst,
                                                     const float* __restrict__ ew,
                                                     int* __restrict__ bfill,
                                                     int2* __restrict__ binned,
                                                     int E, int B) {
    __shared__ int cnt[2048];
    __shared__ int base[2048];
    int tid = threadIdx.x;
    int nchunks = (E + SCHUNK - 1) / SCHUNK;

    for (int c = blockIdx.x; c < nchunks; c += gridDim.x) {
        int lo = c * SCHUNK;
        int hi = min(lo + SCHUNK, E);
        int full = lo + ((hi - lo) & ~3);

        for (int i = tid; i < B; i += 512) cnt[i] = 0;
        __syncthreads();

        // pass A: count
        for (int i = lo + tid * 4; i < full; i += 2048) {
            int4 d = *(const int4*)(edst + i);
            atomicAdd(&cnt[d.x >> NBSH], 1);
            atomicAdd(&cnt[d.y >> NBSH], 1);
            atomicAdd(&cnt[d.z >> NBSH], 1);
            atomicAdd(&cnt[d.w >> NBSH], 1);
        }
        for (int i = full + tid; i < hi; i += 512) atomicAdd(&cnt[edst[i] >> NBSH], 1);
        __syncthreads();

        // claim: one atomic per touched bucket
        for (int i = tid; i < B; i += 512) {
            int c0 = cnt[i];
            base[i] = c0 ? atomicAdd(&bfill[i], c0) : 0;
            cnt[i] = 0;                       // reuse as local fill
        }
        __syncthreads();

        // pass B: write contiguous runs
        for (int i = lo + tid * 4; i < full; i += 2048) {
            int4   s = *(const int4*)(esrc + i);
            int4   d = *(const int4*)(edst + i);
            float4 w = *(const float4*)(ew + i);
            int b0 = d.x >> NBSH, b1 = d.y >> NBSH, b2 = d.z >> NBSH, b3 = d.w >> NBSH;
            int p;
            p = base[b0] + atomicAdd(&cnt[b0], 1);
            binned[p] = make_int2(s.x | ((d.x & (NPB - 1)) << 17), __float_as_int(w.x));
            p = base[b1] + atomicAdd(&cnt[b1], 1);
            binned[p] = make_int2(s.y | ((d.y & (NPB - 1)) << 17), __float_as_int(w.y));
            p = base[b2] + atomicAdd(&cnt[b2], 1);
            binned[p] = make_int2(s.z | ((d.z & (NPB - 1)) << 17), __float_as_int(w.z));
            p = base[b3] + atomicAdd(&cnt[b3], 1);
            binned[p] = make_int2(s.w | ((d.w & (NPB - 1)) << 17), __float_as_int(w.w));
        }
        for (int i = full + tid; i < hi; i += 512) {
            int dd = edst[i];
            int b = dd >> NBSH;
            int p = base[b] + atomicAdd(&cnt[b], 1);
            binned[p] = make_int2(esrc[i] | ((dd & (NPB - 1)) << 17), __float_as_int(ew[i]));
        }
        __syncthreads();
    }
}

// one block per bucket: sort descs by node in place; emit (beg,end) segments.
__global__ __launch_bounds__(256) void refine_kernel(const int* __restrict__ boff,
                                                     int2* __restrict__ binned,
                                                     int2* __restrict__ nodeseg, int N) {
    __shared__ int2 stage[RCAP];        // 48 KB
    __shared__ int  cnt[NPB];
    __shared__ int  pref[NPB + 1];
    __shared__ int  fill[NPB];

    int b = blockIdx.x;
    int node0 = b << NBSH;
    int beg = boff[b], end = boff[b + 1];
    int count = end - beg;

    for (int i = threadIdx.x; i < NPB; i += 256) cnt[i] = 0;
    __syncthreads();

    if (count <= RCAP) {
        for (int i = threadIdx.x; i < count; i += 256) {
            int2 d = binned[beg + i];
            stage[i] = d;
            atomicAdd(&cnt[(d.x >> 17) & (NPB - 1)], 1);
        }
        __syncthreads();
        if (threadIdx.x == 0) {
            int run = 0;
            for (int k = 0; k < NPB; ++k) { pref[k] = run; run += cnt[k]; }
            pref[NPB] = run;
        }
        __syncthreads();
        if (threadIdx.x < NPB) {
            fill[threadIdx.x] = pref[threadIdx.x];
            int n = node0 + threadIdx.x;
            if (n < N)
                nodeseg[n] = make_int2(beg + pref[threadIdx.x],
                                       beg + pref[threadIdx.x + 1]);
        }
        __syncthreads();
        for (int i = threadIdx.x; i < count; i += 256) {
            int2 d = stage[i];
            int p = atomicAdd(&fill[(d.x >> 17) & (NPB - 1)], 1);
            binned[beg + p] = d;
        }
    } else {
        if (threadIdx.x < NPB) {
            int n = node0 + threadIdx.x;
            if (n < N) nodeseg[n] = make_int2(beg, end);
        }
    }
}

// one 64-lane wave per dst node; acc = x[node] + sum x[src]*w over segment.
template<bool BF16>
__global__ __launch_bounds__(256) void node_gather(const uint* __restrict__ xb,
                                                   const float* __restrict__ x,
                                                   const int2* __restrict__ nodeseg,
                                                   const int2* __restrict__ binned,
                                                   float* __restrict__ out, int N) {
    int node = blockIdx.x * 4 + (threadIdx.x >> 6);
    if (node >= N) return;
    int lane = threadIdx.x & 63;
    int2 seg = nodeseg[node];
    int beg = seg.x, end = seg.y;
    int mydl = node & (NPB - 1);

    float a0 = x[(size_t)node * 128 + lane];        // residual
    float a1 = x[(size_t)node * 128 + lane + 64];

    int e = beg;
    for (; e + 3 < end; e += 4) {
        int2 d0 = binned[e], d1 = binned[e + 1], d2 = binned[e + 2], d3 = binned[e + 3];
        float w0 = (((d0.x >> 17) & (NPB - 1)) == mydl) ? __int_as_float(d0.y) : 0.0f;
        float w1 = (((d1.x >> 17) & (NPB - 1)) == mydl) ? __int_as_float(d1.y) : 0.0f;
        float w2 = (((d2.x >> 17) & (NPB - 1)) == mydl) ? __int_as_float(d2.y) : 0.0f;
        float w3 = (((d3.x >> 17) & (NPB - 1)) == mydl) ? __int_as_float(d3.y) : 0.0f;
        if (BF16) {
            uint p0 = xb[(size_t)(d0.x & 0x1FFFF) * 64 + lane];
            uint p1 = xb[(size_t)(d1.x & 0x1FFFF) * 64 + lane];
            uint p2 = xb[(size_t)(d2.x & 0x1FFFF) * 64 + lane];
            uint p3 = xb[(size_t)(d3.x & 0x1FFFF) * 64 + lane];
            a0 = fmaf(__uint_as_float(p0 << 16), w0, a0);
            a1 = fmaf(__uint_as_float(p0 & 0xFFFF0000u), w0, a1);
            a0 = fmaf(__uint_as_float(p1 << 16), w1, a0);
            a1 = fmaf(__uint_as_float(p1 & 0xFFFF0000u), w1, a1);
            a0 = fmaf(__uint_as_float(p2 << 16), w2, a0);
            a1 = fmaf(__uint_as_float(p2 & 0xFFFF0000u), w2, a1);
            a0 = fmaf(__uint_as_float(p3 << 16), w3, a0);
            a1 = fmaf(__uint_as_float(p3 & 0xFFFF0000u), w3, a1);
        } else {
            float u0 = x[(size_t)(d0.x & 0x1FFFF) * 128 + lane];
            float v0 = x[(size_t)(d0.x & 0x1FFFF) * 128 + lane + 64];
            float u1 = x[(size_t)(d1.x & 0x1FFFF) * 128 + lane];
            float v1 = x[(size_t)(d1.x & 0x1FFFF) * 128 + lane + 64];
            float u2 = x[(size_t)(d2.x & 0x1FFFF) * 128 + lane];
            float v2 = x[(size_t)(d2.x & 0x1FFFF) * 128 + lane + 64];
            float u3 = x[(size_t)(d3.x & 0x1FFFF) * 128 + lane];
            float v3 = x[(size_t)(d3.x & 0x1FFFF) * 128 + lane + 64];
            a0 = fmaf(u0, w0, a0); a1 = fmaf(v0, w0, a1);
            a0 = fmaf(u1, w1, a0); a1 = fmaf(v1, w1, a1);
            a0 = fmaf(u2, w2, a0); a1 = fmaf(v2, w2, a1);
            a0 = fmaf(u3, w3, a0); a1 = fmaf(v3, w3, a1);
        }
    }
    for (; e < end; ++e) {
        int2 d0 = binned[e];
        float w0 = (((d0.x >> 17) & (NPB - 1)) == mydl) ? __int_as_float(d0.y) : 0.0f;
        if (BF16) {
            uint p0 = xb[(size_t)(d0.x & 0x1FFFF) * 64 + lane];
            a0 = fmaf(__uint_as_float(p0 << 16), w0, a0);
            a1 = fmaf(__uint_as_float(p0 & 0xFFFF0000u), w0, a1);
        } else {
            float u0 = x[(size_t)(d0.x & 0x1FFFF) * 128 + lane];
            float v0 = x[(size_t)(d0.x & 0x1FFFF) * 128 + lane + 64];
            a0 = fmaf(u0, w0, a0); a1 = fmaf(v0, w0, a1);
        }
    }

    out[(size_t)node * 128 + lane]      = a0;
    out[(size_t)node * 128 + lane + 64] = a1;
}

// ------------------------------------------------- fallback atomic path

__global__ __launch_bounds__(256) void copy_kernel(const float4* __restrict__ src,
                                                   float4* __restrict__ dst, int n4) {
    int i = blockIdx.x * 256 + threadIdx.x;
    if (i < n4) dst[i] = src[i];
}

__global__ __launch_bounds__(256) void scatter_kernel(const float* __restrict__ x,
                                                      const int* __restrict__ esrc,
                                                      const int* __restrict__ edst,
                                                      const float* __restrict__ ew,
                                                      float* __restrict__ agg, int E) {
    int e = blockIdx.x * 8 + (threadIdx.x >> 5);
    if (e >= E) return;
    int lane = threadIdx.x & 31;
    int s = esrc[e];
    int d = edst[e];
    float w = ew[e];
    float4 v = ((const float4*)(x + (size_t)s * 128))[lane];
    float* dp = agg + (size_t)d * 128 + lane * 4;
    atomicAdd(dp + 0, v.x * w);
    atomicAdd(dp + 1, v.y * w);
    atomicAdd(dp + 2, v.z * w);
    atomicAdd(dp + 3, v.w * w);
}

// ----------------------------------------- fused MLP (both layers, MFMA bf16)
// h (f32, in d_out) -> selu(h@W1+b1) -> selu(.@W2+b2) -> d_out (f32), in place.
// A-frag: row = lane&15, k = (lane>>4)*8+j (contiguous). B from Wt[n][k]
// ("B^T" layout): col = lane&15, k-slice contiguous. D: col = lane&15,
// row = (lane>>4)*4 + reg  [m89-verified mapping].
// LDS bf16 tiles, XOR swizzle: ushort idx ^= (row&7)<<3 (16B-block granular).
__global__ __launch_bounds__(256) void mlp_fused(const float* __restrict__ h,
                                                 const float* __restrict__ W1,
                                                 const float* __restrict__ b1,
                                                 const float* __restrict__ W2,
                                                 const float* __restrict__ b2,
                                                 float* __restrict__ outp, int nrows) {
    __shared__ unsigned short sW1[128 * 128];   // Wt1[n][k] bf16, 32 KB
    __shared__ unsigned short sW2[128 * 128];   // Wt2[n][k] bf16, 32 KB
    __shared__ unsigned short sH[MROWS * 128];  // h-tile bf16, 8 KB (reused for h2)

    int tid  = threadIdx.x;
    int row0 = blockIdx.x * MROWS;

    // ---- stage Wt = W^T in bf16 (reads are L2-resident broadcasts) ----
    for (int i = tid; i < 128 * 64; i += 256) {
        int n = i & 127, kp = i >> 7;           // k pair = (2kp, 2kp+1)
        uint lo = bf16r(W1[(2 * kp) * 128 + n]);
        uint hi = bf16r(W1[(2 * kp + 1) * 128 + n]);
        ((uint*)sW1)[(((n * 128 + 2 * kp) ^ ((n & 7) << 3)) >> 1)] = lo | (hi << 16);
        lo = bf16r(W2[(2 * kp) * 128 + n]);
        hi = bf16r(W2[(2 * kp + 1) * 128 + n]);
        ((uint*)sW2)[(((n * 128 + 2 * kp) ^ ((n & 7) << 3)) >> 1)] = lo | (hi << 16);
    }
    // ---- stage h tile bf16 ----
    for (int i = tid; i < MROWS * 32; i += 256) {
        int r = i >> 5, cg = i & 31;
        float4 v = (row0 + r < nrows) ? ((const float4*)h)[(size_t)(row0 + r) * 32 + cg]
                                      : make_float4(0.f, 0.f, 0.f, 0.f);
        uint p0 = bf16r(v.x) | (bf16r(v.y) << 16);
        uint p1 = bf16r(v.z) | (bf16r(v.w) << 16);
        int us = (r * 128 + cg * 4) ^ ((r & 7) << 3);
        ((uint*)sH)[us >> 1]       = p0;
        ((uint*)sH)[(us >> 1) + 1] = p1;
    }
    __syncthreads();

    int lane = tid & 63;
    int wid  = tid >> 6;
    int rbase = (wid & 1) * 16;     // wave's 16-row tile within block
    int cbase = (wid >> 1) * 64;    // wave's 64-col half
    int lr = lane & 15;             // frag row/col selector
    int lq = lane >> 4;             // k-group

    // ---- layer 1 ----
    f32x4 acc[4];
    #pragma unroll
    for (int t = 0; t < 4; ++t) acc[t] = (f32x4){0.f, 0.f, 0.f, 0.f};

    #pragma unroll
    for (int kk = 0; kk < 4; ++kk) {
        int r = rbase + lr;
        int k = lq * 8 + kk * 32;
        bf16x8 af = *(const bf16x8*)&sH[(r * 128 + k) ^ ((r & 7) << 3)];
        #pragma unroll
        for (int t = 0; t < 4; ++t) {
            int n = cbase + t * 16 + lr;
            bf16x8 bf = *(const bf16x8*)&sW1[(n * 128 + k) ^ ((n & 7) << 3)];
            acc[t] = __builtin_amdgcn_mfma_f32_16x16x32_bf16(af, bf, acc[t], 0, 0, 0);
        }
    }
    __syncthreads();   // everyone done reading sH (layer-1 A-frags)

    // bias + SELU, write h2 (bf16) back into sH
    #pragma unroll
    for (int t = 0; t < 4; ++t) {
        int col = cbase + t * 16 + lr;
        float bv = b1[col];
        #pragma unroll
        for (int g = 0; g < 4; ++g) {
            int row = rbase + lq * 4 + g;
            float v = selu_f(acc[t][g] + bv);
            sH[(row * 128 + col) ^ ((row & 7) << 3)] = (unsigned short)bf16r(v);
        }
    }
    __syncthreads();

    // ---- layer 2 ----
    #pragma unroll
    for (int t = 0; t < 4; ++t) acc[t] = (f32x4){0.f, 0.f, 0.f, 0.f};

    #pragma unroll
    for (int kk = 0; kk < 4; ++kk) {
        int r = rbase + lr;
        int k = lq * 8 + kk * 32;
        bf16x8 af = *(const bf16x8*)&sH[(r * 128 + k) ^ ((r & 7) << 3)];
        #pragma unroll
        for (int t = 0; t < 4; ++t) {
            int n = cbase + t * 16 + lr;
            bf16x8 bf = *(const bf16x8*)&sW2[(n * 128 + k) ^ ((n & 7) << 3)];
            acc[t] = __builtin_amdgcn_mfma_f32_16x16x32_bf16(af, bf, acc[t], 0, 0, 0);
        }
    }

    // bias + SELU, store f32 to global (block owns its rows; in-place safe)
    #pragma unroll
    for (int t = 0; t < 4; ++t) {
        int col = cbase + t * 16 + lr;
        float bv = b2[col];
        #pragma unroll
        for (int g = 0; g < 4; ++g) {
            int row = row0 + rbase + lq * 4 + g;
            if (row < nrows)
                outp[(size_t)row * 128 + col] = selu_f(acc[t][g] + bv);
        }
    }
}

// ----------------------------------------------------------------- f32 GEMM
// (fallback path only)
__global__ __launch_bounds__(256) void gemm_bias_selu(const float* __restrict__ inp,
                                                      const float* __restrict__ W,
                                                      const float* __restrict__ bias,
                                                      float* __restrict__ outp, int nrows) {
    __shared__ float sW[128 * 128];
    __shared__ float sH[32 * 128];

    float4* sW4 = (float4*)sW;
    float4* sH4 = (float4*)sH;

    for (int i = threadIdx.x; i < 128 * 32; i += 256)
        sW4[i] = ((const float4*)W)[i];

    int row0 = blockIdx.x * 32;
    for (int i = threadIdx.x; i < 32 * 32; i += 256) {
        int r = row0 + (i >> 5);
        sH4[i] = (r < nrows) ? ((const float4*)inp)[(size_t)r * 32 + (i & 31)]
                             : make_float4(0.f, 0.f, 0.f, 0.f);
    }
    __syncthreads();

    int cg = threadIdx.x & 31;
    int rg = (threadIdx.x >> 5) << 2;

    float4 acc[4];
    #pragma unroll
    for (int r = 0; r < 4; ++r) acc[r] = make_float4(0.f, 0.f, 0.f, 0.f);

    #pragma unroll 4
    for (int k4 = 0; k4 < 32; ++k4) {
        float4 w0 = sW4[(k4 * 4 + 0) * 32 + cg];
        float4 w1 = sW4[(k4 * 4 + 1) * 32 + cg];
        float4 w2 = sW4[(k4 * 4 + 2) * 32 + cg];
        float4 w3 = sW4[(k4 * 4 + 3) * 32 + cg];
        #pragma unroll
        for (int r = 0; r < 4; ++r) {
            float4 h = sH4[(rg + r) * 32 + k4];
            acc[r].x = fmaf(h.x, w0.x, fmaf(h.y, w1.x, fmaf(h.z, w2.x, fmaf(h.w, w3.x, acc[r].x))));
            acc[r].y = fmaf(h.x, w0.y, fmaf(h.y, w1.y, fmaf(h.z, w2.y, fmaf(h.w, w3.y, acc[r].y))));
            acc[r].z = fmaf(h.x, w0.z, fmaf(h.y, w1.z, fmaf(h.z, w2.z, fmaf(h.w, w3.z, acc[r].z))));
            acc[r].w = fmaf(h.x, w0.w, fmaf(h.y, w1.w, fmaf(h.z, w2.w, fmaf(h.w, w3.w, acc[r].w))));
        }
    }

    float4 bv = ((const float4*)bias)[cg];
    #pragma unroll
    for (int r = 0; r < 4; ++r) {
        int row = row0 + rg + r;
        if (row < nrows) {
            float4 o;
            o.x = selu_f(acc[r].x + bv.x);
            o.y = selu_f(acc[r].y + bv.y);
            o.z = selu_f(acc[r].z + bv.z);
            o.w = selu_f(acc[r].w + bv.w);
            ((float4*)outp)[(size_t)row * 32 + cg] = o;
        }
    }
}

// ---------------------------------------------------------------- launch

extern "C" void kernel_launch(void* const* d_in, const int* in_sizes, int n_in,
                              void* d_out, int out_size, void* d_ws, size_t ws_size,
                              hipStream_t stream) {
    (void)n_in; (void)out_size;
    const float* x    = (const float*)d_in[0];
    const int*   esrc = (const int*)  d_in[1];
    const int*   edst = (const int*)  d_in[2];
    const float* ew   = (const float*)d_in[3];
    const float* W1   = (const float*)d_in[4];
    const float* b1   = (const float*)d_in[5];
    const float* W2   = (const float*)d_in[6];
    const float* b2   = (const float*)d_in[7];
    float* out = (float*)d_out;

    int N = in_sizes[0] / 128;
    int E = in_sizes[1];
    int B = (N + NPB - 1) >> NBSH;

    // ws layout: bcnt(B) | boff(B+1) | bfill(B) | [align16] nodeseg(N int2) |
    //            xb(N*64 uint) | binned(E int2)
    size_t hdr   = ((size_t)(3 * B + 1) * 4 + 15) & ~(size_t)15;
    size_t seg_b = (size_t)N * 8;
    size_t xb_b  = (size_t)N * 256;
    size_t bin_b = (size_t)E * 8;
    size_t need_bf16 = hdr + seg_b + xb_b + bin_b;
    size_t need_f32  = hdr + seg_b + bin_b;

    bool use_bf16 = (ws_size >= need_bf16);
    bool use_csr  = (B <= 2048) && (ws_size >= need_f32) && (N <= 131072);

    if (use_csr) {
        int*  bcnt    = (int*)d_ws;
        int*  boff    = bcnt + B;
        int*  bfill   = boff + B + 1;
        int2* nodeseg = (int2*)((char*)d_ws + hdr);
        uint* xb      = (uint*)((char*)d_ws + hdr + seg_b);
        int2* binned  = (int2*)((char*)d_ws + hdr + seg_b + (use_bf16 ? xb_b : 0));

        hipMemsetAsync(bcnt, 0, (size_t)B * 4, stream);

        if (use_bf16) {
            int total = N * 64;
            to_bf16<<<(total + 255) / 256, 256, 0, stream>>>(x, xb, total);
        }

        bucket_hist<<<512, 256, 0, stream>>>(edst, bcnt, E, B);
        bucket_scan<<<1, 1024, 0, stream>>>(bcnt, boff, bfill, B, E);

        int nchunks = (E + SCHUNK - 1) / SCHUNK; if (nchunks > 2048) nchunks = 2048;
        chunk_scatter<<<nchunks, 512, 0, stream>>>(esrc, edst, ew, bfill, binned, E, B);

        refine_kernel<<<B, 256, 0, stream>>>(boff, binned, nodeseg, N);

        int gb = (N + 3) / 4;
        if (use_bf16)
            node_gather<true><<<gb, 256, 0, stream>>>(xb, x, nodeseg, binned, out, N);
        else
            node_gather<false><<<gb, 256, 0, stream>>>(xb, x, nodeseg, binned, out, N);

        // fused 2-layer MFMA MLP, in place on d_out
        int mblocks = (N + MROWS - 1) / MROWS;
        mlp_fused<<<mblocks, 256, 0, stream>>>(out, W1, b1, W2, b2, out, N);
    } else {
        int n4 = N * 32;
        copy_kernel<<<(n4 + 255) / 256, 256, 0, stream>>>((const float4*)x, (float4*)out, n4);
        scatter_kernel<<<(E + 7) / 8, 256, 0, stream>>>(x, esrc, edst, ew, out, E);
        int gblocks = (N + 31) / 32;
        gemm_bias_selu<<<gblocks, 256, 0, stream>>>(out, W1, b1, out, N);
        gemm_bias_selu<<<gblocks, 256, 0, stream>>>(out, W2, b2, out, N);
    }
}